// Round 1
// baseline (89.582 us; speedup 1.0000x reference)
//
#include <hip/hip_runtime.h>

// 16-bit ripple-borrow subtractor on {0,1} float bits.
// Exact equivalence: per row, pack bits LSB-first into uint16; then
//   diff bits = bits of (a - b) mod 2^16, final borrow = (a < b).
// Memory-bound: 256 MiB read + 136 MiB write => ~62 us floor at 6.3 TB/s.

__global__ __launch_bounds__(256) void sub16_kernel(
    const float* __restrict__ A,
    const float* __restrict__ B,
    float* __restrict__ diff,
    float* __restrict__ borrow,
    int batch)
{
    int i = blockIdx.x * blockDim.x + threadIdx.x;
    if (i >= batch) return;

    const float4* a4 = reinterpret_cast<const float4*>(A + (size_t)i * 16);
    const float4* b4 = reinterpret_cast<const float4*>(B + (size_t)i * 16);

    unsigned a = 0u, b = 0u;
#pragma unroll
    for (int k = 0; k < 4; ++k) {
        float4 av = a4[k];
        float4 bv = b4[k];
        a |= ((unsigned)(av.x != 0.0f)) << (4 * k + 0);
        a |= ((unsigned)(av.y != 0.0f)) << (4 * k + 1);
        a |= ((unsigned)(av.z != 0.0f)) << (4 * k + 2);
        a |= ((unsigned)(av.w != 0.0f)) << (4 * k + 3);
        b |= ((unsigned)(bv.x != 0.0f)) << (4 * k + 0);
        b |= ((unsigned)(bv.y != 0.0f)) << (4 * k + 1);
        b |= ((unsigned)(bv.z != 0.0f)) << (4 * k + 2);
        b |= ((unsigned)(bv.w != 0.0f)) << (4 * k + 3);
    }

    unsigned d  = (a - b) & 0xFFFFu;
    unsigned bo = (a < b) ? 1u : 0u;

    float4* o4 = reinterpret_cast<float4*>(diff + (size_t)i * 16);
#pragma unroll
    for (int k = 0; k < 4; ++k) {
        float4 v;
        v.x = (float)((d >> (4 * k + 0)) & 1u);
        v.y = (float)((d >> (4 * k + 1)) & 1u);
        v.z = (float)((d >> (4 * k + 2)) & 1u);
        v.w = (float)((d >> (4 * k + 3)) & 1u);
        o4[k] = v;
    }
    borrow[i] = (float)bo;
}

extern "C" void kernel_launch(void* const* d_in, const int* in_sizes, int n_in,
                              void* d_out, int out_size, void* d_ws, size_t ws_size,
                              hipStream_t stream) {
    const float* A = (const float*)d_in[0];
    const float* B = (const float*)d_in[1];
    float* out = (float*)d_out;

    int batch = in_sizes[0] / 16;
    float* diff   = out;                        // [batch, 16]
    float* borrow = out + (size_t)batch * 16;   // [batch, 1]

    int block = 256;
    int grid = (batch + block - 1) / block;
    sub16_kernel<<<grid, block, 0, stream>>>(A, B, diff, borrow, batch);
}

// Round 3
// 62.434 us; speedup vs baseline: 1.4348x; 1.4348x over previous
//
#include <hip/hip_runtime.h>

// 16-bit ripple-borrow subtractor on {0,1} float bits.
// Per row: pack bits LSB-first into uint16; diff = (a-b) & 0xFFFF, borrow = a<b.
// Lane-per-float4 layout: thread g owns bits [4q..4q+3] of row g>>2, so every
// global load/store is stride-1 across lanes (fully coalesced). The 16-bit
// words are assembled within each 4-lane group via 2x shfl_xor (A in low
// halfword, B in high halfword of one packed u32).

typedef float vfloat4 __attribute__((ext_vector_type(4)));  // clang-native, OK for nontemporal builtins

__global__ __launch_bounds__(256) void sub16_kernel(
    const vfloat4* __restrict__ A4,
    const vfloat4* __restrict__ B4,
    vfloat4* __restrict__ D4,
    float* __restrict__ borrow,
    int nquads)
{
    int g = blockIdx.x * blockDim.x + threadIdx.x;  // quad index
    if (g >= nquads) return;

    int q   = g & 3;   // quad within row
    int row = g >> 2;

    vfloat4 av = A4[g];
    vfloat4 bv = B4[g];

    unsigned na = (unsigned)(av.x != 0.0f)
                | ((unsigned)(av.y != 0.0f) << 1)
                | ((unsigned)(av.z != 0.0f) << 2)
                | ((unsigned)(av.w != 0.0f) << 3);
    unsigned nb = (unsigned)(bv.x != 0.0f)
                | ((unsigned)(bv.y != 0.0f) << 1)
                | ((unsigned)(bv.z != 0.0f) << 2)
                | ((unsigned)(bv.w != 0.0f) << 3);

    int sh = q << 2;
    unsigned packed = (na << sh) | (nb << (16 + sh));

    // OR-combine across the 4-lane group (lanes differ only in q)
    packed |= __shfl_xor(packed, 1);
    packed |= __shfl_xor(packed, 2);

    unsigned a = packed & 0xFFFFu;
    unsigned b = packed >> 16;
    unsigned d = (a - b) & 0xFFFFu;

    vfloat4 v;
    v.x = (float)((d >> (sh + 0)) & 1u);
    v.y = (float)((d >> (sh + 1)) & 1u);
    v.z = (float)((d >> (sh + 2)) & 1u);
    v.w = (float)((d >> (sh + 3)) & 1u);
    __builtin_nontemporal_store(v, &D4[g]);

    if (q == 0) {
        __builtin_nontemporal_store((float)(a < b), &borrow[row]);
    }
}

extern "C" void kernel_launch(void* const* d_in, const int* in_sizes, int n_in,
                              void* d_out, int out_size, void* d_ws, size_t ws_size,
                              hipStream_t stream) {
    const vfloat4* A4 = (const vfloat4*)d_in[0];
    const vfloat4* B4 = (const vfloat4*)d_in[1];
    float* out = (float*)d_out;

    int batch  = in_sizes[0] / 16;
    int nquads = batch * 4;

    vfloat4* D4   = (vfloat4*)out;              // [batch, 16] floats
    float* borrow = out + (size_t)batch * 16;   // [batch, 1]

    int block = 256;
    int grid  = (nquads + block - 1) / block;
    sub16_kernel<<<grid, block, 0, stream>>>(A4, B4, D4, borrow, nquads);
}